// Round 8
// baseline (432.495 us; speedup 1.0000x reference)
//
#include <hip/hip_runtime.h>
#include <math.h>

typedef _Float16 f16;
typedef _Float16 f16x2 __attribute__((ext_vector_type(2)));
typedef _Float16 f16x4 __attribute__((ext_vector_type(4)));
typedef _Float16 f16x8 __attribute__((ext_vector_type(8)));
typedef float f32x4 __attribute__((ext_vector_type(4)));

#define NVOX 48
#define F_ 16

// K-order (17 kblks, K=544): kq = kblk*4 + ksel, j = half*4 + c.
//  kblk 0..4  : fd=ksel, fh=kblk,          fw=half        (o = ksel*96 + kblk*12 + half)
//  kblk 5..9  : fd=ksel, fh=kblk-5,        fw=2+half      (o = ksel*96 + (kblk-5)*12 + 2 + half)
//  kblk 10,11 : fd=ksel, fh=(kblk-10)*2+half, fw=4        (o = ksel*96 + fh*12 + 4)
//  kblk 12    : fd=ksel, fh=4, fw=4, half1 zero           (o = ksel*96 + 52)
//  kblk 13,14 : fd=4, fh=ksel, fw=(kblk-13)*2+half        (o = 384 + ksel*12 + fw)
//  kblk 15    : fd=4, fh=ksel, fw=4, half1 zero           (o = 384 + ksel*12 + 4)
//  kblk 16    : fd=4, fh=4, fw=ksel*2+half, zero if fw>=5 (o = 432 + ksel*2 + half)
// xs layout: elem = d*96 + h*12 + w (8x8x12 tile + 16-elem zeroed tail).

// ---------------------------------------------------------------------------
// Kernel 1: effective filter bank in MFMA fragment layout.
// efb[kq(68)][n(256)][j(8)] f16. Folds radial shells, degree-shared w, and
// sqrt((m>0?2:1)/(2n+1)) power-spectrum scale. Invalid slots -> 0.
// ---------------------------------------------------------------------------
__global__ void build_filters(const float* __restrict__ w, f16* __restrict__ efb) {
    int e = blockIdx.x * 256 + threadIdx.x;
    if (e >= 68 * 2048) return;
    int j = e & 7;
    int n = (e >> 3) & 255;
    int kq = e >> 11;            // 0..67
    int kblk = kq >> 2, ksel = kq & 3, half = j >> 2, c = j & 3;
    int f = n >> 4, map = n & 15;

    int fd, fh, fw;
    bool valid = true;
    if (kblk < 5)        { fd = ksel; fh = kblk;              fw = half; }
    else if (kblk < 10)  { fd = ksel; fh = kblk - 5;          fw = 2 + half; }
    else if (kblk < 12)  { fd = ksel; fh = (kblk-10)*2 + half; fw = 4; }
    else if (kblk == 12) { fd = ksel; fh = 4; fw = 4;         valid = (half == 0); }
    else if (kblk < 15)  { fd = 4; fh = ksel; fw = (kblk-13)*2 + half; }
    else if (kblk == 15) { fd = 4; fh = ksel; fw = 4;         valid = (half == 0); }
    else                 { fd = 4; fh = 4; fw = ksel*2 + half; valid = (fw < 5); }

    float outv = 0.f;
    if (valid) {
        // meshgrid(indexing='xy'): x = g[fh], y = g[fd], z = g[fw]
        float xx = (float)(fh - 2), yy = (float)(fd - 2), zz = (float)(fw - 2);
        float r = sqrtf(xx * xx + yy * yy + zz * zz);
        float rxy = sqrtf(xx * xx + yy * yy);
        float ct = (r > 0.f) ? zz / r : 0.f;
        float st = sqrtf(fmaxf(0.f, 1.f - ct * ct));
        float cp = (rxy > 0.f) ? xx / rxy : 1.f;
        float sp = (rxy > 0.f) ? yy / rxy : 0.f;
        float c2p = cp * cp - sp * sp, s2p = 2.f * cp * sp;
        float c3p = c2p * cp - s2p * sp, s3p = s2p * cp + c2p * sp;

        const float k00 = 0.28209479177387814f;
        const float k10 = 0.48860251190291992f;
        const float c1v = 0.34549414947133547f;
        const float k20 = 0.31539156525252005f;
        const float c21 = 0.77254840404637908f;
        const float c22 = 0.38627420202318954f;
        const float k30 = 0.37317633259011546f;
        const float c31 = 0.32318018411415065f;
        const float c32 = 1.02198547643328236f;
        const float c33 = 0.41722382363278409f;

        float val;
        int deg;
        switch (map) {
            case 0:  deg = 0; val = k00; break;
            case 1:  deg = 1; val = k10 * ct; break;
            case 2:  deg = 1; val = -c1v * st * cp; break;
            case 3:  deg = 1; val = -c1v * st * sp; break;
            case 4:  deg = 2; val = k20 * (3.f * ct * ct - 1.f); break;
            case 5:  deg = 2; val = -c21 * st * ct * cp; break;
            case 6:  deg = 2; val = -c21 * st * ct * sp; break;
            case 7:  deg = 2; val = c22 * st * st * c2p; break;
            case 8:  deg = 2; val = c22 * st * st * s2p; break;
            case 9:  deg = 3; val = k30 * (5.f * ct * ct * ct - 3.f * ct); break;
            case 10: deg = 3; val = -c31 * st * (5.f * ct * ct - 1.f) * cp; break;
            case 11: deg = 3; val = -c31 * st * (5.f * ct * ct - 1.f) * sp; break;
            case 12: deg = 3; val = c32 * st * st * ct * c2p; break;
            case 13: deg = 3; val = c32 * st * st * ct * s2p; break;
            case 14: deg = 3; val = -c33 * st * st * st * c3p; break;
            default: deg = 3; val = -c33 * st * st * st * s3p; break;
        }
        const float scale_tab[16] = {
            1.f,
            0.57735026918962576f, 0.81649658092772603f, 0.81649658092772603f,
            0.44721359549995794f, 0.63245553203367587f, 0.63245553203367587f,
            0.63245553203367587f, 0.63245553203367587f,
            0.37796447300922720f, 0.53452248382484879f, 0.53452248382484879f,
            0.53452248382484879f, 0.53452248382484879f, 0.53452248382484879f,
            0.53452248382484879f};

        float wsum = 0.f;
#pragma unroll
        for (int i = 0; i < 3; ++i) {
            float rad = fmaxf(0.f, 1.f - fabsf(r - (float)i));
            wsum += rad * w[((c * F_ + f) * 3 + i) * 4 + deg];
        }
        outv = wsum * val * scale_tab[map];
    }
    efb[e] = (f16)outv;
}

// ---------------------------------------------------------------------------
// Kernel 2: MFMA main kernel, swapped operands: mfma(filters, voxels, acc).
// M=128 tile (4x4x8) staged once as 8x8x12 (+zeroed tail), two 4x4x4 subtiles.
// All A-read offsets are lane_base + compile-time immediates (no off_tab).
// ---------------------------------------------------------------------------
__global__ __launch_bounds__(256, 4) void sshconv_main(
    const float* __restrict__ x, const f16* __restrict__ efb,
    const float* __restrict__ w_cp, const float* __restrict__ b_cp,
    const float* __restrict__ bias, const float* __restrict__ w_proj,
    const float* __restrict__ b_proj, float* __restrict__ out) {
    __shared__ f16 xs[784 * 4];          // 8x8x12 voxels x 4ch fp16 + tail (6.1 KB)
    __shared__ f16x2 part2[16 * 64 * 4]; // [f][vox][ksel^f&3] (pa,pb) (16 KB)
    f16* s16 = (f16*)part2;              // overlaid: [vox64][72pad] (9.2 KB)

    const int tid = threadIdx.x;
    const int bt = blockIdx.x;
    const int tw = bt % 6, th = (bt / 6) % 12, td = (bt / 72) % 12, b = bt / 864;
    const int d0 = td * 4, h0 = th * 4, w0 = tw * 8;

    // zero the tail (read only via zero-weight taps; garbage could be NaN)
    if (tid < 16)
        *(f16x4*)&xs[(768 + tid) * 4] = (f16x4){(f16)0.f, (f16)0.f, (f16)0.f, (f16)0.f};

    // stage x tile 8x8x12 (zero halo), fp32 -> fp16, elem = sd*96 + sh*12 + sw
#pragma unroll
    for (int i = 0; i < 3; ++i) {
        int s = i * 256 + tid;  // 0..767
        int sd = s / 96, r = s % 96;
        int sh = r / 12, sw = r % 12;
        int gd = d0 - 2 + sd, gh = h0 - 2 + sh, gw = w0 - 2 + sw;
        float4 v = make_float4(0.f, 0.f, 0.f, 0.f);
        if (gd >= 0 && gd < NVOX && gh >= 0 && gh < NVOX && gw >= 0 && gw < NVOX)
            v = *(const float4*)&x[(((b * NVOX + gd) * NVOX + gh) * NVOX + gw) * 4];
        f16x4 hv = {(f16)v.x, (f16)v.y, (f16)v.z, (f16)v.w};
        *(f16x4*)&xs[s * 4] = hv;
    }
    __syncthreads();

    const int lane = tid & 63, wv = tid >> 6;
    const int col = lane & 15, ksel = lane >> 4;
    const int vh = col >> 2, vw = col & 3;
    const f16* bq = efb + (ksel * 256 + wv * 64 + col) * 8;

    for (int sub = 0; sub < 2; ++sub) {
        const int abase = vh * 12 + vw + sub * 4;
        const int baseA = abase + ksel * 96;        // fd = ksel phases
        const int baseB = abase + 384 + ksel * 12;  // fd = 4, fh = ksel
        const int baseC = abase + 432 + ksel * 2;   // fd = 4, fh = 4, fw = 2*ksel

        f32x4 acc[4][4];  // [nf][vb]
#pragma unroll
        for (int i = 0; i < 4; ++i)
#pragma unroll
            for (int jj = 0; jj < 4; ++jj) acc[i][jj] = (f32x4){0.f, 0.f, 0.f, 0.f};

#define KSTEP(BASE, O0, O1, KB)                                                 \
    {                                                                           \
        f16x8 a[4];                                                             \
        _Pragma("unroll") for (int vb = 0; vb < 4; ++vb) {                      \
            ((f16x4*)&a[vb])[0] = *(const f16x4*)&xs[((BASE) + (O0) + vb*96)*4];\
            ((f16x4*)&a[vb])[1] = *(const f16x4*)&xs[((BASE) + (O1) + vb*96)*4];\
        }                                                                       \
        f16x8 bf[4];                                                            \
        _Pragma("unroll") for (int nf = 0; nf < 4; ++nf)                        \
            bf[nf] = *(const f16x8*)(bq + (KB) * 8192 + nf * 128);              \
        _Pragma("unroll") for (int nf = 0; nf < 4; ++nf)                        \
            _Pragma("unroll") for (int vb = 0; vb < 4; ++vb)                    \
                acc[nf][vb] = __builtin_amdgcn_mfma_f32_16x16x32_f16(           \
                    bf[nf], a[vb], acc[nf][vb], 0, 0, 0);                       \
    }

#pragma unroll 2
        for (int kb = 0; kb < 5; ++kb) KSTEP(baseA, kb * 12, kb * 12 + 1, kb)
#pragma unroll 2
        for (int kb = 5; kb < 10; ++kb) KSTEP(baseA, (kb-5)*12 + 2, (kb-5)*12 + 3, kb)
        KSTEP(baseA, 4, 16, 10)
        KSTEP(baseA, 28, 40, 11)
        KSTEP(baseA, 52, 52, 12)
        KSTEP(baseB, 0, 1, 13)
        KSTEP(baseB, 2, 3, 14)
        KSTEP(baseB, 4, 4, 15)
        KSTEP(baseC, 0, 1, 16)
#undef KSTEP

        // ---- in-register power-spectrum partials -> part2 ----
        float wcp[4][4], bcp[4];
#pragma unroll
        for (int nf = 0; nf < 4; ++nf) {
            const int f = wv * 4 + nf;
            bcp[nf] = b_cp[f];
#pragma unroll
            for (int c = 0; c < 4; ++c) wcp[nf][c] = w_cp[c * F_ + f];
        }

#pragma unroll
        for (int vb = 0; vb < 4; ++vb) {
            f16x4 xc = *(const f16x4*)&xs[((vb + 2) * 96 + (vh + 2) * 12 +
                                           (vw + sub * 4 + 2)) * 4];
            const float xc0 = (float)xc[0], xc1 = (float)xc[1];
            const float xc2 = (float)xc[2], xc3 = (float)xc[3];
            const int vox = vb * 16 + col;
#pragma unroll
            for (int nf = 0; nf < 4; ++nf) {
                const f32x4 v = acc[nf][vb];
                float cen = bcp[nf] + xc0 * wcp[nf][0] + xc1 * wcp[nf][1] +
                            xc2 * wcp[nf][2] + xc3 * wcp[nf][3];
                float v0 = v[0] + ((ksel == 0) ? cen : 0.f);
                float s0 = v0 * v0, s1 = v[1] * v[1], s2 = v[2] * v[2], s3 = v[3] * v[3];
                float pa = (ksel & 1) ? (s0 + s1) : s0;
                float pb = (ksel & 1) ? (s2 + s3) : (s1 + s2 + s3);
                const int f = wv * 4 + nf;
                part2[(f * 64 + vox) * 4 + (ksel ^ (f & 3))] = (f16x2){(f16)pa, (f16)pb};
            }
        }
        __syncthreads();

        // ---- combine partials + bias + signed-log -> regs ----
        f16 so_all[16];
        {
            const int fc = tid >> 4, vlo = tid & 15;
            const int kx = fc & 3;
            const f32x4 bias4 = *(const f32x4*)&bias[fc * 4];
#pragma unroll
            for (int it = 0; it < 4; ++it) {
                const int vox = it * 16 + vlo;
                const int base = (fc * 64 + vox) * 4;
                f16x2 p0 = part2[base + (0 ^ kx)];
                f16x2 p1 = part2[base + (1 ^ kx)];
                f16x2 p2 = part2[base + (2 ^ kx)];
                f16x2 p3 = part2[base + (3 ^ kx)];
                f32x4 sv = {(float)p0[0], (float)p0[1],
                            (float)p1[0] + (float)p1[1] + (float)p2[0],
                            (float)p2[1] + (float)p3[0] + (float)p3[1]};
#pragma unroll
                for (int n = 0; n < 4; ++n) {
                    float vb2 = sv[n] + bias4[n];
                    float lg = __builtin_amdgcn_logf(1.f + fabsf(vb2)) * 0.69314718055994531f;
                    so_all[it * 4 + n] = (f16)copysignf(lg, vb2);
                }
            }
        }
        __syncthreads();  // all part2 reads done before overlay writes

        // ---- write s16 (overlaid on part2) ----
        {
            const int fc = tid >> 4, vlo = tid & 15;
#pragma unroll
            for (int it = 0; it < 4; ++it) {
                const int vox = it * 16 + vlo;
                *(f16x4*)&s16[vox * 72 + fc * 4] = *(f16x4*)&so_all[it * 4];
            }
        }

        // ---- projection via MFMA: s16[64][64] x w_proj[64][16] ----
        const int fo = lane & 15, kg = lane >> 4;
        f16 wb0[8], wb1[8];
#pragma unroll
        for (int j = 0; j < 8; ++j) {
            wb0[j] = (f16)w_proj[(kg * 8 + j) * F_ + fo];
            wb1[j] = (f16)w_proj[(32 + kg * 8 + j) * F_ + fo];
        }
        const float bpj = b_proj[fo];
        __syncthreads();

        f16x8 a0 = *(const f16x8*)&s16[(wv * 16 + col) * 72 + kg * 8];
        f16x8 a1 = *(const f16x8*)&s16[(wv * 16 + col) * 72 + 32 + kg * 8];
        f32x4 oc = {0.f, 0.f, 0.f, 0.f};
        oc = __builtin_amdgcn_mfma_f32_16x16x32_f16(a0, *(f16x8*)wb0, oc, 0, 0, 0);
        oc = __builtin_amdgcn_mfma_f32_16x16x32_f16(a1, *(f16x8*)wb1, oc, 0, 0, 0);

#pragma unroll
        for (int r = 0; r < 4; ++r) {
            float o = fmaxf(oc[r] + bpj, 0.f);
            out[(((b * NVOX + d0 + wv) * NVOX + h0 + kg) * NVOX + w0 + sub * 4 + r) * F_ + fo] = o;
        }
        __syncthreads();  // protect s16/part2 overlay before next subtile writes
    }
}

extern "C" void kernel_launch(void* const* d_in, const int* in_sizes, int n_in,
                              void* d_out, int out_size, void* d_ws, size_t ws_size,
                              hipStream_t stream) {
    const float* x = (const float*)d_in[0];       // [2,48,48,48,4]
    const float* w = (const float*)d_in[1];       // [4,16,3,4]
    const float* w_cp = (const float*)d_in[2];    // [4,16]
    const float* b_cp = (const float*)d_in[3];    // [16]
    const float* bias = (const float*)d_in[4];    // [64]
    const float* w_proj = (const float*)d_in[5];  // [64,16]
    const float* b_proj = (const float*)d_in[6];  // [16]
    float* out = (float*)d_out;                   // [2,48,48,48,16]
    f16* efb = (f16*)d_ws;                        // 139264 f16 (272 KB)

    build_filters<<<544, 256, 0, stream>>>(w, efb);
    sshconv_main<<<1728, 256, 0, stream>>>(x, efb, w_cp, b_cp, bias, w_proj, b_proj, out);
}

// Round 9
// 432.358 us; speedup vs baseline: 1.0003x; 1.0003x over previous
//
#include <hip/hip_runtime.h>
#include <math.h>

typedef _Float16 f16;
typedef _Float16 f16x2 __attribute__((ext_vector_type(2)));
typedef _Float16 f16x4 __attribute__((ext_vector_type(4)));
typedef _Float16 f16x8 __attribute__((ext_vector_type(8)));
typedef float f32x4 __attribute__((ext_vector_type(4)));

#define NVOX 48
#define F_ 16

// K-order (17 kblks, K=544): kq = kblk*4 + ksel, j = half*4 + c.
//  kblk 0..4  : fd=ksel, fh=kblk,          fw=half        (o = ksel*96 + kblk*12 + half)
//  kblk 5..9  : fd=ksel, fh=kblk-5,        fw=2+half      (o = ksel*96 + (kblk-5)*12 + 2 + half)
//  kblk 10,11 : fd=ksel, fh=(kblk-10)*2+half, fw=4        (o = ksel*96 + fh*12 + 4)
//  kblk 12    : fd=ksel, fh=4, fw=4, half1 zero           (o = ksel*96 + 52)
//  kblk 13,14 : fd=4, fh=ksel, fw=(kblk-13)*2+half        (o = 384 + ksel*12 + fw)
//  kblk 15    : fd=4, fh=ksel, fw=4, half1 zero           (o = 384 + ksel*12 + 4)
//  kblk 16    : fd=4, fh=4, fw=ksel*2+half, zero if fw>=5 (o = 432 + ksel*2 + half)
// xs layout: elem = d*96 + h*12 + w (8x8x12 tile + 16-elem zeroed tail).

// ---------------------------------------------------------------------------
// Kernel 1: effective filter bank in MFMA fragment layout.
// efb[kq(68)][n(256)][j(8)] f16. Folds radial shells, degree-shared w, and
// sqrt((m>0?2:1)/(2n+1)) power-spectrum scale. Invalid slots -> 0.
// ---------------------------------------------------------------------------
__global__ void build_filters(const float* __restrict__ w, f16* __restrict__ efb) {
    int e = blockIdx.x * 256 + threadIdx.x;
    if (e >= 68 * 2048) return;
    int j = e & 7;
    int n = (e >> 3) & 255;
    int kq = e >> 11;            // 0..67
    int kblk = kq >> 2, ksel = kq & 3, half = j >> 2, c = j & 3;
    int f = n >> 4, map = n & 15;

    int fd, fh, fw;
    bool valid = true;
    if (kblk < 5)        { fd = ksel; fh = kblk;              fw = half; }
    else if (kblk < 10)  { fd = ksel; fh = kblk - 5;          fw = 2 + half; }
    else if (kblk < 12)  { fd = ksel; fh = (kblk-10)*2 + half; fw = 4; }
    else if (kblk == 12) { fd = ksel; fh = 4; fw = 4;         valid = (half == 0); }
    else if (kblk < 15)  { fd = 4; fh = ksel; fw = (kblk-13)*2 + half; }
    else if (kblk == 15) { fd = 4; fh = ksel; fw = 4;         valid = (half == 0); }
    else                 { fd = 4; fh = 4; fw = ksel*2 + half; valid = (fw < 5); }

    float outv = 0.f;
    if (valid) {
        // meshgrid(indexing='xy'): x = g[fh], y = g[fd], z = g[fw]
        float xx = (float)(fh - 2), yy = (float)(fd - 2), zz = (float)(fw - 2);
        float r = sqrtf(xx * xx + yy * yy + zz * zz);
        float rxy = sqrtf(xx * xx + yy * yy);
        float ct = (r > 0.f) ? zz / r : 0.f;
        float st = sqrtf(fmaxf(0.f, 1.f - ct * ct));
        float cp = (rxy > 0.f) ? xx / rxy : 1.f;
        float sp = (rxy > 0.f) ? yy / rxy : 0.f;
        float c2p = cp * cp - sp * sp, s2p = 2.f * cp * sp;
        float c3p = c2p * cp - s2p * sp, s3p = s2p * cp + c2p * sp;

        const float k00 = 0.28209479177387814f;
        const float k10 = 0.48860251190291992f;
        const float c1v = 0.34549414947133547f;
        const float k20 = 0.31539156525252005f;
        const float c21 = 0.77254840404637908f;
        const float c22 = 0.38627420202318954f;
        const float k30 = 0.37317633259011546f;
        const float c31 = 0.32318018411415065f;
        const float c32 = 1.02198547643328236f;
        const float c33 = 0.41722382363278409f;

        float val;
        int deg;
        switch (map) {
            case 0:  deg = 0; val = k00; break;
            case 1:  deg = 1; val = k10 * ct; break;
            case 2:  deg = 1; val = -c1v * st * cp; break;
            case 3:  deg = 1; val = -c1v * st * sp; break;
            case 4:  deg = 2; val = k20 * (3.f * ct * ct - 1.f); break;
            case 5:  deg = 2; val = -c21 * st * ct * cp; break;
            case 6:  deg = 2; val = -c21 * st * ct * sp; break;
            case 7:  deg = 2; val = c22 * st * st * c2p; break;
            case 8:  deg = 2; val = c22 * st * st * s2p; break;
            case 9:  deg = 3; val = k30 * (5.f * ct * ct * ct - 3.f * ct); break;
            case 10: deg = 3; val = -c31 * st * (5.f * ct * ct - 1.f) * cp; break;
            case 11: deg = 3; val = -c31 * st * (5.f * ct * ct - 1.f) * sp; break;
            case 12: deg = 3; val = c32 * st * st * ct * c2p; break;
            case 13: deg = 3; val = c32 * st * st * ct * s2p; break;
            case 14: deg = 3; val = -c33 * st * st * st * c3p; break;
            default: deg = 3; val = -c33 * st * st * st * s3p; break;
        }
        const float scale_tab[16] = {
            1.f,
            0.57735026918962576f, 0.81649658092772603f, 0.81649658092772603f,
            0.44721359549995794f, 0.63245553203367587f, 0.63245553203367587f,
            0.63245553203367587f, 0.63245553203367587f,
            0.37796447300922720f, 0.53452248382484879f, 0.53452248382484879f,
            0.53452248382484879f, 0.53452248382484879f, 0.53452248382484879f,
            0.53452248382484879f};

        float wsum = 0.f;
#pragma unroll
        for (int i = 0; i < 3; ++i) {
            float rad = fmaxf(0.f, 1.f - fabsf(r - (float)i));
            wsum += rad * w[((c * F_ + f) * 3 + i) * 4 + deg];
        }
        outv = wsum * val * scale_tab[map];
    }
    efb[e] = (f16)outv;
}

// ---------------------------------------------------------------------------
// Kernel 2: MFMA main kernel, swapped operands: mfma(filters, voxels, acc).
// M=128 tile (4x4x8) staged once as 8x8x12 (+zeroed tail), two 4x4x4 subtiles.
// All A-read offsets are lane_base + compile-time immediates (no off_tab).
// A-frags assembled with __builtin_shufflevector (SSA — no alloca/scratch).
// ---------------------------------------------------------------------------
__global__ __launch_bounds__(256, 4) void sshconv_main(
    const float* __restrict__ x, const f16* __restrict__ efb,
    const float* __restrict__ w_cp, const float* __restrict__ b_cp,
    const float* __restrict__ bias, const float* __restrict__ w_proj,
    const float* __restrict__ b_proj, float* __restrict__ out) {
    __shared__ f16 xs[784 * 4];          // 8x8x12 voxels x 4ch fp16 + tail (6.1 KB)
    __shared__ f16x2 part2[16 * 64 * 4]; // [f][vox][ksel^f&3] (pa,pb) (16 KB)
    f16* s16 = (f16*)part2;              // overlaid: [vox64][72pad] (9.2 KB)

    const int tid = threadIdx.x;
    const int bt = blockIdx.x;
    const int tw = bt % 6, th = (bt / 6) % 12, td = (bt / 72) % 12, b = bt / 864;
    const int d0 = td * 4, h0 = th * 4, w0 = tw * 8;

    // zero the tail (read only via zero-weight taps; garbage could be NaN)
    if (tid < 16)
        *(f16x4*)&xs[(768 + tid) * 4] = (f16x4){(f16)0.f, (f16)0.f, (f16)0.f, (f16)0.f};

    // stage x tile 8x8x12 (zero halo), fp32 -> fp16, elem = sd*96 + sh*12 + sw
#pragma unroll
    for (int i = 0; i < 3; ++i) {
        int s = i * 256 + tid;  // 0..767
        int sd = s / 96, r = s % 96;
        int sh = r / 12, sw = r % 12;
        int gd = d0 - 2 + sd, gh = h0 - 2 + sh, gw = w0 - 2 + sw;
        float4 v = make_float4(0.f, 0.f, 0.f, 0.f);
        if (gd >= 0 && gd < NVOX && gh >= 0 && gh < NVOX && gw >= 0 && gw < NVOX)
            v = *(const float4*)&x[(((b * NVOX + gd) * NVOX + gh) * NVOX + gw) * 4];
        f16x4 hv = {(f16)v.x, (f16)v.y, (f16)v.z, (f16)v.w};
        *(f16x4*)&xs[s * 4] = hv;
    }
    __syncthreads();

    const int lane = tid & 63, wv = tid >> 6;
    const int col = lane & 15, ksel = lane >> 4;
    const int vh = col >> 2, vw = col & 3;
    const f16* bq = efb + (ksel * 256 + wv * 64 + col) * 8;

    for (int sub = 0; sub < 2; ++sub) {
        const int abase = vh * 12 + vw + sub * 4;
        const int baseA = abase + ksel * 96;        // fd = ksel phases
        const int baseB = abase + 384 + ksel * 12;  // fd = 4, fh = ksel
        const int baseC = abase + 432 + ksel * 2;   // fd = 4, fh = 4, fw = 2*ksel

        f32x4 acc[4][4];  // [nf][vb]
#pragma unroll
        for (int i = 0; i < 4; ++i)
#pragma unroll
            for (int jj = 0; jj < 4; ++jj) acc[i][jj] = (f32x4){0.f, 0.f, 0.f, 0.f};

#define KSTEP(BASE, O0, O1, KB)                                                 \
    {                                                                           \
        f16x8 a[4];                                                             \
        _Pragma("unroll") for (int vb = 0; vb < 4; ++vb) {                      \
            f16x4 lo = *(const f16x4*)&xs[((BASE) + (O0) + vb * 96) * 4];       \
            f16x4 hi = *(const f16x4*)&xs[((BASE) + (O1) + vb * 96) * 4];       \
            a[vb] = __builtin_shufflevector(lo, hi, 0, 1, 2, 3, 4, 5, 6, 7);    \
        }                                                                       \
        f16x8 bf[4];                                                            \
        _Pragma("unroll") for (int nf = 0; nf < 4; ++nf)                        \
            bf[nf] = *(const f16x8*)(bq + (KB) * 8192 + nf * 128);              \
        _Pragma("unroll") for (int nf = 0; nf < 4; ++nf)                        \
            _Pragma("unroll") for (int vb = 0; vb < 4; ++vb)                    \
                acc[nf][vb] = __builtin_amdgcn_mfma_f32_16x16x32_f16(           \
                    bf[nf], a[vb], acc[nf][vb], 0, 0, 0);                       \
    }

#pragma unroll 2
        for (int kb = 0; kb < 5; ++kb) KSTEP(baseA, kb * 12, kb * 12 + 1, kb)
#pragma unroll 2
        for (int kb = 5; kb < 10; ++kb) KSTEP(baseA, (kb-5)*12 + 2, (kb-5)*12 + 3, kb)
        KSTEP(baseA, 4, 16, 10)
        KSTEP(baseA, 28, 40, 11)
        KSTEP(baseA, 52, 52, 12)
        KSTEP(baseB, 0, 1, 13)
        KSTEP(baseB, 2, 3, 14)
        KSTEP(baseB, 4, 4, 15)
        KSTEP(baseC, 0, 1, 16)
#undef KSTEP

        // ---- in-register power-spectrum partials -> part2 ----
        float wcp[4][4], bcp[4];
#pragma unroll
        for (int nf = 0; nf < 4; ++nf) {
            const int f = wv * 4 + nf;
            bcp[nf] = b_cp[f];
#pragma unroll
            for (int c = 0; c < 4; ++c) wcp[nf][c] = w_cp[c * F_ + f];
        }

#pragma unroll
        for (int vb = 0; vb < 4; ++vb) {
            f16x4 xc = *(const f16x4*)&xs[((vb + 2) * 96 + (vh + 2) * 12 +
                                           (vw + sub * 4 + 2)) * 4];
            const float xc0 = (float)xc[0], xc1 = (float)xc[1];
            const float xc2 = (float)xc[2], xc3 = (float)xc[3];
            const int vox = vb * 16 + col;
#pragma unroll
            for (int nf = 0; nf < 4; ++nf) {
                const f32x4 v = acc[nf][vb];
                float cen = bcp[nf] + xc0 * wcp[nf][0] + xc1 * wcp[nf][1] +
                            xc2 * wcp[nf][2] + xc3 * wcp[nf][3];
                float v0 = v[0] + ((ksel == 0) ? cen : 0.f);
                float s0 = v0 * v0, s1 = v[1] * v[1], s2 = v[2] * v[2], s3 = v[3] * v[3];
                float pa = (ksel & 1) ? (s0 + s1) : s0;
                float pb = (ksel & 1) ? (s2 + s3) : (s1 + s2 + s3);
                const int f = wv * 4 + nf;
                part2[(f * 64 + vox) * 4 + (ksel ^ (f & 3))] = (f16x2){(f16)pa, (f16)pb};
            }
        }
        __syncthreads();

        // ---- combine partials + bias + signed-log -> regs ----
        f16 so_all[16];
        {
            const int fc = tid >> 4, vlo = tid & 15;
            const int kx = fc & 3;
            const f32x4 bias4 = *(const f32x4*)&bias[fc * 4];
#pragma unroll
            for (int it = 0; it < 4; ++it) {
                const int vox = it * 16 + vlo;
                const int base = (fc * 64 + vox) * 4;
                f16x2 p0 = part2[base + (0 ^ kx)];
                f16x2 p1 = part2[base + (1 ^ kx)];
                f16x2 p2 = part2[base + (2 ^ kx)];
                f16x2 p3 = part2[base + (3 ^ kx)];
                f32x4 sv = {(float)p0[0], (float)p0[1],
                            (float)p1[0] + (float)p1[1] + (float)p2[0],
                            (float)p2[1] + (float)p3[0] + (float)p3[1]};
#pragma unroll
                for (int n = 0; n < 4; ++n) {
                    float vb2 = sv[n] + bias4[n];
                    float lg = __builtin_amdgcn_logf(1.f + fabsf(vb2)) * 0.69314718055994531f;
                    so_all[it * 4 + n] = (f16)copysignf(lg, vb2);
                }
            }
        }
        __syncthreads();  // all part2 reads done before overlay writes

        // ---- write s16 (overlaid on part2) ----
        {
            const int fc = tid >> 4, vlo = tid & 15;
#pragma unroll
            for (int it = 0; it < 4; ++it) {
                const int vox = it * 16 + vlo;
                *(f16x4*)&s16[vox * 72 + fc * 4] = *(f16x4*)&so_all[it * 4];
            }
        }

        // ---- projection via MFMA: s16[64][64] x w_proj[64][16] ----
        const int fo = lane & 15, kg = lane >> 4;
        f16 wb0[8], wb1[8];
#pragma unroll
        for (int j = 0; j < 8; ++j) {
            wb0[j] = (f16)w_proj[(kg * 8 + j) * F_ + fo];
            wb1[j] = (f16)w_proj[(32 + kg * 8 + j) * F_ + fo];
        }
        const float bpj = b_proj[fo];
        __syncthreads();

        f16x8 a0 = *(const f16x8*)&s16[(wv * 16 + col) * 72 + kg * 8];
        f16x8 a1 = *(const f16x8*)&s16[(wv * 16 + col) * 72 + 32 + kg * 8];
        f32x4 oc = {0.f, 0.f, 0.f, 0.f};
        oc = __builtin_amdgcn_mfma_f32_16x16x32_f16(a0, *(f16x8*)wb0, oc, 0, 0, 0);
        oc = __builtin_amdgcn_mfma_f32_16x16x32_f16(a1, *(f16x8*)wb1, oc, 0, 0, 0);

#pragma unroll
        for (int r = 0; r < 4; ++r) {
            float o = fmaxf(oc[r] + bpj, 0.f);
            out[(((b * NVOX + d0 + wv) * NVOX + h0 + kg) * NVOX + w0 + sub * 4 + r) * F_ + fo] = o;
        }
        __syncthreads();  // protect s16/part2 overlay before next subtile writes
    }
}

extern "C" void kernel_launch(void* const* d_in, const int* in_sizes, int n_in,
                              void* d_out, int out_size, void* d_ws, size_t ws_size,
                              hipStream_t stream) {
    const float* x = (const float*)d_in[0];       // [2,48,48,48,4]
    const float* w = (const float*)d_in[1];       // [4,16,3,4]
    const float* w_cp = (const float*)d_in[2];    // [4,16]
    const float* b_cp = (const float*)d_in[3];    // [16]
    const float* bias = (const float*)d_in[4];    // [64]
    const float* w_proj = (const float*)d_in[5];  // [64,16]
    const float* b_proj = (const float*)d_in[6];  // [16]
    float* out = (float*)d_out;                   // [2,48,48,48,16]
    f16* efb = (f16*)d_ws;                        // 139264 f16 (272 KB)

    build_filters<<<544, 256, 0, stream>>>(w, efb);
    sshconv_main<<<1728, 256, 0, stream>>>(x, efb, w_cp, b_cp, bias, w_proj, b_proj, out);
}

// Round 10
// 78.241 us; speedup vs baseline: 5.5277x; 5.5260x over previous
//
#include <hip/hip_runtime.h>
#include <math.h>

typedef _Float16 f16;
typedef _Float16 f16x2 __attribute__((ext_vector_type(2)));
typedef _Float16 f16x4 __attribute__((ext_vector_type(4)));
typedef _Float16 f16x8 __attribute__((ext_vector_type(8)));
typedef float f32x4 __attribute__((ext_vector_type(4)));

#define NVOX 48
#define F_ 16

// K-order for stage 1 (128 taps): k<100: w-adjacent pairs p=k>>1 over rows
// (fd,fh)=p>>1, fw0=(p&1)*2; k in [100,125): singles fw=4, s=k-100; k>=125 pad.
// xs1 planar: xs1[c][d*80 + h*10 + w]  (4 planes x 656 f16).
// y: [map(16)][vox(64)][kslot(16)] f16, kslot = ((c+map)&3)*4 + rp  (rp 3 = pad;
//    map0 pads hold x_center for the fused central-pixel conv).

__device__ __forceinline__ float sh_val(int map, int fd, int fh, int fw) {
    // meshgrid(indexing='xy'): x = g[fh], y = g[fd], z = g[fw]
    float xx = (float)(fh - 2), yy = (float)(fd - 2), zz = (float)(fw - 2);
    float r = sqrtf(xx * xx + yy * yy + zz * zz);
    float rxy = sqrtf(xx * xx + yy * yy);
    float ct = (r > 0.f) ? zz / r : 0.f;
    float st = sqrtf(fmaxf(0.f, 1.f - ct * ct));
    float cp = (rxy > 0.f) ? xx / rxy : 1.f;
    float sp = (rxy > 0.f) ? yy / rxy : 0.f;
    float c2p = cp * cp - sp * sp, s2p = 2.f * cp * sp;
    float c3p = c2p * cp - s2p * sp, s3p = s2p * cp + c2p * sp;
    const float k00 = 0.28209479177387814f;
    const float k10 = 0.48860251190291992f;
    const float c1v = 0.34549414947133547f;
    const float k20 = 0.31539156525252005f;
    const float c21 = 0.77254840404637908f;
    const float c22 = 0.38627420202318954f;
    const float k30 = 0.37317633259011546f;
    const float c31 = 0.32318018411415065f;
    const float c32 = 1.02198547643328236f;
    const float c33 = 0.41722382363278409f;
    switch (map) {
        case 0:  return k00;
        case 1:  return k10 * ct;
        case 2:  return -c1v * st * cp;
        case 3:  return -c1v * st * sp;
        case 4:  return k20 * (3.f * ct * ct - 1.f);
        case 5:  return -c21 * st * ct * cp;
        case 6:  return -c21 * st * ct * sp;
        case 7:  return c22 * st * st * c2p;
        case 8:  return c22 * st * st * s2p;
        case 9:  return k30 * (5.f * ct * ct * ct - 3.f * ct);
        case 10: return -c31 * st * (5.f * ct * ct - 1.f) * cp;
        case 11: return -c31 * st * (5.f * ct * ct - 1.f) * sp;
        case 12: return c32 * st * st * ct * c2p;
        case 13: return c32 * st * st * ct * s2p;
        case 14: return -c33 * st * st * st * c3p;
        default: return -c33 * st * st * st * s3p;
    }
}

// ---------------------------------------------------------------------------
// Kernel 1: builds
//  ag  (6144 f16): stage-1 atom B-frags, ag[((kb*3+nt)*4+ksel)*16+map][j=8],
//                  value = rad(|tap|, rp=nt) * Y(map, tap(k)), k=kb*32+ksel*8+j
//  w2g (4096 f16): stage-2 B-frags, w2g[map][f][kslot], kslot=((c+map)&3)*4+rp:
//                  rp<3 -> w[c,f,rp,deg(map)]*sqrt_scale[map]; map0 pad -> w_cp.
// ---------------------------------------------------------------------------
__global__ void build_filters(const float* __restrict__ w,
                              const float* __restrict__ w_cp,
                              f16* __restrict__ ws) {
    int e = blockIdx.x * 256 + threadIdx.x;  // 0..10239
    const int degmap[16] = {0,1,1,1,2,2,2,2,2,3,3,3,3,3,3,3};
    const float sscale[16] = {
        1.f,
        0.57735026918962576f, 0.81649658092772603f, 0.81649658092772603f,
        0.44721359549995794f, 0.63245553203367587f, 0.63245553203367587f,
        0.63245553203367587f, 0.63245553203367587f,
        0.37796447300922720f, 0.53452248382484879f, 0.53452248382484879f,
        0.53452248382484879f, 0.53452248382484879f, 0.53452248382484879f,
        0.53452248382484879f};
    if (e < 6144) {
        int j = e & 7, map = (e >> 3) & 15, ksel = (e >> 7) & 3, ntkb = e >> 9;
        int kb = ntkb / 3, nt = ntkb % 3;
        int k = kb * 32 + ksel * 8 + j;
        float v = 0.f;
        if (k < 125) {
            int fd, fh, fw;
            if (k < 100) { int p = k >> 1, row = p >> 1;
                           fd = row / 5; fh = row % 5; fw = (p & 1) * 2 + (k & 1); }
            else         { int s = k - 100; fd = s / 5; fh = s % 5; fw = 4; }
            float xx = (float)(fh - 2), yy = (float)(fd - 2), zz = (float)(fw - 2);
            float r = sqrtf(xx * xx + yy * yy + zz * zz);
            float rad = fmaxf(0.f, 1.f - fabsf(r - (float)nt));
            v = rad * sh_val(map, fd, fh, fw);
        }
        ws[e] = (f16)v;
    } else {
        int e2 = e - 6144;
        int kp = e2 & 15, f = (e2 >> 4) & 15, map = e2 >> 8;
        int rp = kp & 3, c = ((kp >> 2) - map) & 3;
        float v = 0.f;
        if (rp < 3)      v = w[((c * F_ + f) * 3 + rp) * 4 + degmap[map]] * sscale[map];
        else if (map == 0) v = w_cp[c * F_ + f];
        ws[6144 + e2] = (f16)v;
    }
}

// ---------------------------------------------------------------------------
// Kernel 2: two-stage MFMA.
// Stage 1: mfma(x-frag, atom-frag): D rows=(vox,c) [vox=wv*16+q*4+ksel, c=reg],
//          cols = map; acc over K=128 taps; 3 n-tiles (rp). -> y in LDS (f16).
// Stage 2: per map: mfma(y-frag, w2-frag): D rows=vox, cols=f; square-accum
//          per-degree spec in registers (central folded into map0 K-pads).
// Epilogue: bias + signed-log -> s16 (overlay on y) -> projection MFMA.
// ---------------------------------------------------------------------------
__global__ __launch_bounds__(256, 4) void sshconv_main(
    const float* __restrict__ x, const f16* __restrict__ ag,
    const f16* __restrict__ w2g, const float* __restrict__ b_cp,
    const float* __restrict__ bias, const float* __restrict__ w_proj,
    const float* __restrict__ b_proj, float* __restrict__ out) {
    __shared__ f16 xs1[4 * 656];      // planar x tile (5.1 KB)
    __shared__ int tabP[48];          // pair base offsets
    __shared__ int tabS[32];          // kb3 per-k offsets
    __shared__ f16 ybuf[16 * 64 * 16];// y (32 KB); s16 overlays after stage 2
    f16* s16 = (f16*)ybuf;            // [vox64][72pad]

    const int tid = threadIdx.x;
    const int bt = blockIdx.x;
    const int tw = bt % 12, th = (bt / 12) % 12, td = (bt / 144) % 12, b = bt / 1728;
    const int d0 = td * 4, h0 = th * 4, w0 = tw * 4;

    if (tid < 48) {
        int p = tid, row = p >> 1;
        tabP[p] = (row / 5) * 80 + (row % 5) * 10 + (p & 1) * 2;
    } else if (tid < 80) {
        int kk = tid - 48, k = 96 + kk, o;
        if (k < 100)      { int p = k >> 1, row = p >> 1;
                            o = (row / 5) * 80 + (row % 5) * 10 + (p & 1) * 2 + (k & 1); }
        else if (k < 125) { int s = k - 100; o = (s / 5) * 80 + (s % 5) * 10 + 4; }
        else              { o = 0; }  // pad: reads real (finite) data x 0-atom
        tabS[kk] = o;
    }

    // stage x tile: 512 halo voxels as 256 w-pairs, planar fp16
    {
        int sp = tid;
        int sd = sp >> 5, sh = (sp >> 2) & 7, sw2 = (sp & 3) * 2;
        int gd = d0 - 2 + sd, gh = h0 - 2 + sh, gw0 = w0 - 2 + sw2, gw1 = gw0 + 1;
        float4 v0 = make_float4(0.f, 0.f, 0.f, 0.f), v1 = v0;
        bool okd = (gd >= 0 && gd < NVOX && gh >= 0 && gh < NVOX);
        if (okd && gw0 >= 0 && gw0 < NVOX)
            v0 = *(const float4*)&x[(((b * NVOX + gd) * NVOX + gh) * NVOX + gw0) * 4];
        if (okd && gw1 >= 0 && gw1 < NVOX)
            v1 = *(const float4*)&x[(((b * NVOX + gd) * NVOX + gh) * NVOX + gw1) * 4];
        int sb = sd * 80 + sh * 10 + sw2;
        *(f16x2*)&xs1[0 * 656 + sb] = (f16x2){(f16)v0.x, (f16)v1.x};
        *(f16x2*)&xs1[1 * 656 + sb] = (f16x2){(f16)v0.y, (f16)v1.y};
        *(f16x2*)&xs1[2 * 656 + sb] = (f16x2){(f16)v0.z, (f16)v1.z};
        *(f16x2*)&xs1[3 * 656 + sb] = (f16x2){(f16)v0.w, (f16)v1.w};
    }
    __syncthreads();

    const int lane = tid & 63, wv = tid >> 6;
    const int am = lane & 15, ksel = lane >> 4;
    const int cm = am & 3, vhm = am >> 2;
    const int apos0 = cm * 656 + wv * 80 + vhm * 10;

    // per-lane tap offsets (static-indexed arrays, fully unrolled usage)
    int oP[12], oS[8];
#pragma unroll
    for (int kb = 0; kb < 3; ++kb)
#pragma unroll
        for (int t = 0; t < 4; ++t) oP[kb * 4 + t] = tabP[kb * 16 + ksel * 4 + t];
#pragma unroll
    for (int j = 0; j < 8; ++j) oS[j] = tabS[ksel * 8 + j];

    // ---- stage 1 ----
#pragma unroll
    for (int q = 0; q < 4; ++q) {
        const int ap = apos0 + q;
        f32x4 acc1[3];
#pragma unroll
        for (int nt = 0; nt < 3; ++nt) acc1[nt] = (f32x4){0.f, 0.f, 0.f, 0.f};

#pragma unroll
        for (int kb = 0; kb < 4; ++kb) {
            f16x8 af;
            if (kb < 3) {
                if ((q & 1) == 0) {
                    f16x2 p0 = *(const f16x2*)&xs1[ap + oP[kb * 4 + 0]];
                    f16x2 p1 = *(const f16x2*)&xs1[ap + oP[kb * 4 + 1]];
                    f16x2 p2 = *(const f16x2*)&xs1[ap + oP[kb * 4 + 2]];
                    f16x2 p3 = *(const f16x2*)&xs1[ap + oP[kb * 4 + 3]];
                    f16x4 lo = __builtin_shufflevector(p0, p1, 0, 1, 2, 3);
                    f16x4 hi = __builtin_shufflevector(p2, p3, 0, 1, 2, 3);
                    af = __builtin_shufflevector(lo, hi, 0, 1, 2, 3, 4, 5, 6, 7);
                } else {
                    f16 e0 = xs1[ap + oP[kb * 4 + 0]], e1 = xs1[ap + oP[kb * 4 + 0] + 1];
                    f16 e2 = xs1[ap + oP[kb * 4 + 1]], e3 = xs1[ap + oP[kb * 4 + 1] + 1];
                    f16 e4 = xs1[ap + oP[kb * 4 + 2]], e5 = xs1[ap + oP[kb * 4 + 2] + 1];
                    f16 e6 = xs1[ap + oP[kb * 4 + 3]], e7 = xs1[ap + oP[kb * 4 + 3] + 1];
                    af = (f16x8){e0, e1, e2, e3, e4, e5, e6, e7};
                }
            } else {
                f16 e0 = xs1[ap + oS[0]], e1 = xs1[ap + oS[1]];
                f16 e2 = xs1[ap + oS[2]], e3 = xs1[ap + oS[3]];
                f16 e4 = xs1[ap + oS[4]], e5 = xs1[ap + oS[5]];
                f16 e6 = xs1[ap + oS[6]], e7 = xs1[ap + oS[7]];
                af = (f16x8){e0, e1, e2, e3, e4, e5, e6, e7};
            }
#pragma unroll
            for (int nt = 0; nt < 3; ++nt) {
                f16x8 bf = *(const f16x8*)&ag[(((kb * 3 + nt) * 4 + ksel) * 16 + am) * 8];
                acc1[nt] = __builtin_amdgcn_mfma_f32_16x16x32_f16(af, bf, acc1[nt], 0, 0, 0);
            }
        }

        // y write: lane map=am, vox = wv*16 + q*4 + ksel; 4 channels (regs)
        const int vox = wv * 16 + q * 4 + ksel;
        const int cbase = (wv + 2) * 80 + (ksel + 2) * 10 + (q + 2);
        f16 xc0 = xs1[0 * 656 + cbase], xc1 = xs1[1 * 656 + cbase];
        f16 xc2 = xs1[2 * 656 + cbase], xc3 = xs1[3 * 656 + cbase];
        const bool ism0 = (am == 0);
        {
            f16x4 yw = {(f16)acc1[0][0], (f16)acc1[1][0], (f16)acc1[2][0],
                        ism0 ? xc0 : (f16)0.f};
            *(f16x4*)&ybuf[am * 1024 + vox * 16 + ((0 + am) & 3) * 4] = yw;
        }
        {
            f16x4 yw = {(f16)acc1[0][1], (f16)acc1[1][1], (f16)acc1[2][1],
                        ism0 ? xc1 : (f16)0.f};
            *(f16x4*)&ybuf[am * 1024 + vox * 16 + ((1 + am) & 3) * 4] = yw;
        }
        {
            f16x4 yw = {(f16)acc1[0][2], (f16)acc1[1][2], (f16)acc1[2][2],
                        ism0 ? xc2 : (f16)0.f};
            *(f16x4*)&ybuf[am * 1024 + vox * 16 + ((2 + am) & 3) * 4] = yw;
        }
        {
            f16x4 yw = {(f16)acc1[0][3], (f16)acc1[1][3], (f16)acc1[2][3],
                        ism0 ? xc3 : (f16)0.f};
            *(f16x4*)&ybuf[am * 1024 + vox * 16 + ((3 + am) & 3) * 4] = yw;
        }
    }

    // ---- stage 2 (same-wave y consumption; no barrier needed) ----
    const int degmap[16] = {0,1,1,1,2,2,2,2,2,3,3,3,3,3,3,3};
    const float bcpv = b_cp[am];
    f32x4 spec[4];
#pragma unroll
    for (int n = 0; n < 4; ++n) spec[n] = (f32x4){0.f, 0.f, 0.f, 0.f};

#pragma unroll
    for (int map = 0; map < 16; ++map) {
        f16x8 yl = *(const f16x8*)&ybuf[map * 1024 + (wv * 16 + am) * 16 + (ksel & 1) * 8];
        f16x8 wl = *(const f16x8*)&w2g[map * 256 + am * 16 + (ksel & 1) * 8];
        f16x8 zz8 = (f16x8){(f16)0.f,(f16)0.f,(f16)0.f,(f16)0.f,
                            (f16)0.f,(f16)0.f,(f16)0.f,(f16)0.f};
        f16x8 ya = (ksel < 2) ? yl : zz8;
        f16x8 wa = (ksel < 2) ? wl : zz8;
        f32x4 d2 = __builtin_amdgcn_mfma_f32_16x16x32_f16(
            ya, wa, (f32x4){0.f, 0.f, 0.f, 0.f}, 0, 0, 0);
        if (map == 0) {
            f32x4 bb = {bcpv, bcpv, bcpv, bcpv};
            d2 = d2 + bb;
        }
        spec[degmap[map]] += d2 * d2;
    }

    // ---- bias + signed-log in regs ----
    const f32x4 bias4 = *(const f32x4*)&bias[am * 4];
    f16x4 srow[4];
#pragma unroll
    for (int r = 0; r < 4; ++r) {
#pragma unroll
        for (int n = 0; n < 4; ++n) {
            float v = spec[n][r] + bias4[n];
            float lg = __builtin_amdgcn_logf(1.f + fabsf(v)) * 0.69314718055994531f;
            srow[r][n] = (f16)copysignf(lg, v);
        }
    }
    __syncthreads();  // all waves done reading y before s16 overlay writes
#pragma unroll
    for (int r = 0; r < 4; ++r) {
        const int vox = wv * 16 + ksel * 4 + r;
        *(f16x4*)&s16[vox * 72 + am * 4] = srow[r];
    }

    // ---- projection via MFMA: s16[64][64] x w_proj[64][16] ----
    const int fo = am, kg = ksel;
    f16 wb0[8], wb1[8];
#pragma unroll
    for (int j = 0; j < 8; ++j) {
        wb0[j] = (f16)w_proj[(kg * 8 + j) * F_ + fo];
        wb1[j] = (f16)w_proj[(32 + kg * 8 + j) * F_ + fo];
    }
    const float bpj = b_proj[fo];

    f16x8 a0 = *(const f16x8*)&s16[(wv * 16 + am) * 72 + kg * 8];
    f16x8 a1 = *(const f16x8*)&s16[(wv * 16 + am) * 72 + 32 + kg * 8];
    f32x4 oc = {0.f, 0.f, 0.f, 0.f};
    oc = __builtin_amdgcn_mfma_f32_16x16x32_f16(a0, *(f16x8*)wb0, oc, 0, 0, 0);
    oc = __builtin_amdgcn_mfma_f32_16x16x32_f16(a1, *(f16x8*)wb1, oc, 0, 0, 0);

    // D rows = kg*4+r -> vox = wv*16+kg*4+r -> (vd=wv, vw=kg, vh=r)
#pragma unroll
    for (int r = 0; r < 4; ++r) {
        float o = fmaxf(oc[r] + bpj, 0.f);
        out[(((b * NVOX + d0 + wv) * NVOX + (h0 + r)) * NVOX + (w0 + kg)) * F_ + fo] = o;
    }
}

extern "C" void kernel_launch(void* const* d_in, const int* in_sizes, int n_in,
                              void* d_out, int out_size, void* d_ws, size_t ws_size,
                              hipStream_t stream) {
    const float* x = (const float*)d_in[0];       // [2,48,48,48,4]
    const float* w = (const float*)d_in[1];       // [4,16,3,4]
    const float* w_cp = (const float*)d_in[2];    // [4,16]
    const float* b_cp = (const float*)d_in[3];    // [16]
    const float* bias = (const float*)d_in[4];    // [64]
    const float* w_proj = (const float*)d_in[5];  // [64,16]
    const float* b_proj = (const float*)d_in[6];  // [16]
    float* out = (float*)d_out;                   // [2,48,48,48,16]
    f16* ws = (f16*)d_ws;                         // ag 6144 + w2g 4096 f16

    build_filters<<<40, 256, 0, stream>>>(w, w_cp, ws);
    sshconv_main<<<3456, 256, 0, stream>>>(x, ws, ws + 6144, b_cp, bias,
                                           w_proj, b_proj, out);
}

// Round 11
// 37.123 us; speedup vs baseline: 11.6504x; 2.1076x over previous
//
#include <hip/hip_runtime.h>
#include <math.h>

typedef _Float16 f16;
typedef _Float16 f16x2 __attribute__((ext_vector_type(2)));
typedef _Float16 f16x4 __attribute__((ext_vector_type(4)));
typedef _Float16 f16x8 __attribute__((ext_vector_type(8)));
typedef float f32x4 __attribute__((ext_vector_type(4)));

#define NVOX 48
#define F_ 16

// K-order for stage 1 (128 taps): k<100: w-adjacent pairs p=k>>1 over rows
// (fd,fh)=p>>1, fw0=(p&1)*2; k in [100,125): singles fw=4, s=k-100; k>=125 pad.
// xs1 planar: xs1[c][d*80 + h*10 + w]  (4 planes x 656 f16).
// y: [map(16)][vox(64)][kslot(16)] f16, kslot = ((c+map)&3)*4 + rp  (rp 3 = pad;
//    map0 pads hold x_center for the fused central-pixel conv).

__device__ __forceinline__ float sh_val(int map, int fd, int fh, int fw) {
    // meshgrid(indexing='xy'): x = g[fh], y = g[fd], z = g[fw]
    float xx = (float)(fh - 2), yy = (float)(fd - 2), zz = (float)(fw - 2);
    float r = sqrtf(xx * xx + yy * yy + zz * zz);
    float rxy = sqrtf(xx * xx + yy * yy);
    float ct = (r > 0.f) ? zz / r : 0.f;
    float st = sqrtf(fmaxf(0.f, 1.f - ct * ct));
    float cp = (rxy > 0.f) ? xx / rxy : 1.f;
    float sp = (rxy > 0.f) ? yy / rxy : 0.f;
    float c2p = cp * cp - sp * sp, s2p = 2.f * cp * sp;
    float c3p = c2p * cp - s2p * sp, s3p = s2p * cp + c2p * sp;
    const float k00 = 0.28209479177387814f;
    const float k10 = 0.48860251190291992f;
    const float c1v = 0.34549414947133547f;
    const float k20 = 0.31539156525252005f;
    const float c21 = 0.77254840404637908f;
    const float c22 = 0.38627420202318954f;
    const float k30 = 0.37317633259011546f;
    const float c31 = 0.32318018411415065f;
    const float c32 = 1.02198547643328236f;
    const float c33 = 0.41722382363278409f;
    switch (map) {
        case 0:  return k00;
        case 1:  return k10 * ct;
        case 2:  return -c1v * st * cp;
        case 3:  return -c1v * st * sp;
        case 4:  return k20 * (3.f * ct * ct - 1.f);
        case 5:  return -c21 * st * ct * cp;
        case 6:  return -c21 * st * ct * sp;
        case 7:  return c22 * st * st * c2p;
        case 8:  return c22 * st * st * s2p;
        case 9:  return k30 * (5.f * ct * ct * ct - 3.f * ct);
        case 10: return -c31 * st * (5.f * ct * ct - 1.f) * cp;
        case 11: return -c31 * st * (5.f * ct * ct - 1.f) * sp;
        case 12: return c32 * st * st * ct * c2p;
        case 13: return c32 * st * st * ct * s2p;
        case 14: return -c33 * st * st * st * c3p;
        default: return -c33 * st * st * st * s3p;
    }
}

// ---------------------------------------------------------------------------
// Kernel 1 (identical to round 10): ag (6144 f16) stage-1 atom B-frags,
// w2g (4096 f16) stage-2 B-frags with central-pixel fold into map0 pads.
// ---------------------------------------------------------------------------
__global__ void build_filters(const float* __restrict__ w,
                              const float* __restrict__ w_cp,
                              f16* __restrict__ ws) {
    int e = blockIdx.x * 256 + threadIdx.x;  // 0..10239
    const int degmap[16] = {0,1,1,1,2,2,2,2,2,3,3,3,3,3,3,3};
    const float sscale[16] = {
        1.f,
        0.57735026918962576f, 0.81649658092772603f, 0.81649658092772603f,
        0.44721359549995794f, 0.63245553203367587f, 0.63245553203367587f,
        0.63245553203367587f, 0.63245553203367587f,
        0.37796447300922720f, 0.53452248382484879f, 0.53452248382484879f,
        0.53452248382484879f, 0.53452248382484879f, 0.53452248382484879f,
        0.53452248382484879f};
    if (e < 6144) {
        int j = e & 7, map = (e >> 3) & 15, ksel = (e >> 7) & 3, ntkb = e >> 9;
        int kb = ntkb / 3, nt = ntkb % 3;
        int k = kb * 32 + ksel * 8 + j;
        float v = 0.f;
        if (k < 125) {
            int fd, fh, fw;
            if (k < 100) { int p = k >> 1, row = p >> 1;
                           fd = row / 5; fh = row % 5; fw = (p & 1) * 2 + (k & 1); }
            else         { int s = k - 100; fd = s / 5; fh = s % 5; fw = 4; }
            float xx = (float)(fh - 2), yy = (float)(fd - 2), zz = (float)(fw - 2);
            float r = sqrtf(xx * xx + yy * yy + zz * zz);
            float rad = fmaxf(0.f, 1.f - fabsf(r - (float)nt));
            v = rad * sh_val(map, fd, fh, fw);
        }
        ws[e] = (f16)v;
    } else {
        int e2 = e - 6144;
        int kp = e2 & 15, f = (e2 >> 4) & 15, map = e2 >> 8;
        int rp = kp & 3, c = ((kp >> 2) - map) & 3;
        float v = 0.f;
        if (rp < 3)      v = w[((c * F_ + f) * 3 + rp) * 4 + degmap[map]] * sscale[map];
        else if (map == 0) v = w_cp[c * F_ + f];
        ws[6144 + e2] = (f16)v;
    }
}

__device__ __forceinline__ f16x8 cmb(f16x2 a, f16x2 b, f16x2 c, f16x2 d) {
    f16x4 lo = __builtin_shufflevector(a, b, 0, 1, 2, 3);
    f16x4 hi = __builtin_shufflevector(c, d, 0, 1, 2, 3);
    return __builtin_shufflevector(lo, hi, 0, 1, 2, 3, 4, 5, 6, 7);
}
__device__ __forceinline__ f16x2 sh1(f16x2 a, f16x2 b) {
    return __builtin_shufflevector(a, b, 1, 2);
}

// ---------------------------------------------------------------------------
// Kernel 2: two-stage MFMA, latency-optimized.
// Stage 1: per (kb,pair) load 3 aligned dwords ONCE (q-invariant addresses);
// all 4 q-fragments derived by register shuffles. acc[q][nt] = 12 ILP chains.
// Stage 2: dense K=16 MFMA (16x16x16f16) over y kslots; spec in registers.
// ---------------------------------------------------------------------------
__global__ __launch_bounds__(256, 4) void sshconv_main(
    const float* __restrict__ x, const f16* __restrict__ ag,
    const f16* __restrict__ w2g, const float* __restrict__ b_cp,
    const float* __restrict__ bias, const float* __restrict__ w_proj,
    const float* __restrict__ b_proj, float* __restrict__ out) {
    __shared__ f16 xs1[4 * 656];      // planar x tile (5.1 KB)
    __shared__ int tabP[48];          // pair base offsets
    __shared__ int tabS[32];          // kb3 per-k offsets
    __shared__ f16 ybuf[16 * 64 * 16];// y (32 KB); s16 overlays after stage 2
    f16* s16 = (f16*)ybuf;            // [vox64][72pad]

    const int tid = threadIdx.x;
    const int bt = blockIdx.x;
    const int tw = bt % 12, th = (bt / 12) % 12, td = (bt / 144) % 12, b = bt / 1728;
    const int d0 = td * 4, h0 = th * 4, w0 = tw * 4;

    if (tid < 48) {
        int p = tid, row = p >> 1;
        tabP[p] = (row / 5) * 80 + (row % 5) * 10 + (p & 1) * 2;
    } else if (tid < 80) {
        int kk = tid - 48, k = 96 + kk, o;
        if (k < 100)      { int p = k >> 1, row = p >> 1;
                            o = (row / 5) * 80 + (row % 5) * 10 + (p & 1) * 2 + (k & 1); }
        else if (k < 125) { int s = k - 100; o = (s / 5) * 80 + (s % 5) * 10 + 4; }
        else              { o = 0; }  // pad: reads real (finite) data x 0-atom
        tabS[kk] = o;
    }

    // stage x tile: 512 halo voxels as 256 w-pairs, planar fp16
    {
        int sp = tid;
        int sd = sp >> 5, sh = (sp >> 2) & 7, sw2 = (sp & 3) * 2;
        int gd = d0 - 2 + sd, gh = h0 - 2 + sh, gw0 = w0 - 2 + sw2, gw1 = gw0 + 1;
        float4 v0 = make_float4(0.f, 0.f, 0.f, 0.f), v1 = v0;
        bool okd = (gd >= 0 && gd < NVOX && gh >= 0 && gh < NVOX);
        if (okd && gw0 >= 0 && gw0 < NVOX)
            v0 = *(const float4*)&x[(((b * NVOX + gd) * NVOX + gh) * NVOX + gw0) * 4];
        if (okd && gw1 >= 0 && gw1 < NVOX)
            v1 = *(const float4*)&x[(((b * NVOX + gd) * NVOX + gh) * NVOX + gw1) * 4];
        int sb = sd * 80 + sh * 10 + sw2;
        *(f16x2*)&xs1[0 * 656 + sb] = (f16x2){(f16)v0.x, (f16)v1.x};
        *(f16x2*)&xs1[1 * 656 + sb] = (f16x2){(f16)v0.y, (f16)v1.y};
        *(f16x2*)&xs1[2 * 656 + sb] = (f16x2){(f16)v0.z, (f16)v1.z};
        *(f16x2*)&xs1[3 * 656 + sb] = (f16x2){(f16)v0.w, (f16)v1.w};
    }
    __syncthreads();

    const int lane = tid & 63, wv = tid >> 6;
    const int am = lane & 15, ksel = lane >> 4;
    const int cm = am & 3, vhm = am >> 2;
    const int apos0 = cm * 656 + wv * 80 + vhm * 10;

    // per-lane tap offsets (static-indexed arrays, fully unrolled usage)
    int oP[12], oS[8];
#pragma unroll
    for (int kb = 0; kb < 3; ++kb)
#pragma unroll
        for (int t = 0; t < 4; ++t) oP[kb * 4 + t] = tabP[kb * 16 + ksel * 4 + t];
#pragma unroll
    for (int j = 0; j < 8; ++j) oS[j] = tabS[ksel * 8 + j];

    // ---- stage 1 ----
    f32x4 acc[4][3];  // [q][nt]
#pragma unroll
    for (int q = 0; q < 4; ++q)
#pragma unroll
        for (int nt = 0; nt < 3; ++nt) acc[q][nt] = (f32x4){0.f, 0.f, 0.f, 0.f};

#pragma unroll
    for (int kb = 0; kb < 4; ++kb) {
        f16x8 fr[4];
        if (kb < 3) {
            f16x2 da[4], db[4], dc[4];
#pragma unroll
            for (int t = 0; t < 4; ++t) {
                const f16* p = &xs1[apos0 + oP[kb * 4 + t]];
                da[t] = *(const f16x2*)p;        // elems o, o+1
                db[t] = *(const f16x2*)(p + 2);  // elems o+2, o+3
                dc[t] = *(const f16x2*)(p + 4);  // elems o+4, o+5
            }
            fr[0] = cmb(da[0], da[1], da[2], da[3]);
            fr[1] = cmb(sh1(da[0], db[0]), sh1(da[1], db[1]),
                        sh1(da[2], db[2]), sh1(da[3], db[3]));
            fr[2] = cmb(db[0], db[1], db[2], db[3]);
            fr[3] = cmb(sh1(db[0], dc[0]), sh1(db[1], dc[1]),
                        sh1(db[2], dc[2]), sh1(db[3], dc[3]));
        } else {
            f16x2 sa[8], sb[8];
#pragma unroll
            for (int j2 = 0; j2 < 8; ++j2) {
                const f16* p = &xs1[apos0 + oS[j2]];
                sa[j2] = *(const f16x2*)p;        // elems o, o+1
                sb[j2] = *(const f16x2*)(p + 2);  // elems o+2, o+3
            }
            fr[0] = (f16x8){sa[0][0], sa[1][0], sa[2][0], sa[3][0],
                            sa[4][0], sa[5][0], sa[6][0], sa[7][0]};
            fr[1] = (f16x8){sa[0][1], sa[1][1], sa[2][1], sa[3][1],
                            sa[4][1], sa[5][1], sa[6][1], sa[7][1]};
            fr[2] = (f16x8){sb[0][0], sb[1][0], sb[2][0], sb[3][0],
                            sb[4][0], sb[5][0], sb[6][0], sb[7][0]};
            fr[3] = (f16x8){sb[0][1], sb[1][1], sb[2][1], sb[3][1],
                            sb[4][1], sb[5][1], sb[6][1], sb[7][1]};
        }
#pragma unroll
        for (int nt = 0; nt < 3; ++nt) {
            f16x8 bf = *(const f16x8*)&ag[(((kb * 3 + nt) * 4 + ksel) * 16 + am) * 8];
#pragma unroll
            for (int q = 0; q < 4; ++q)
                acc[q][nt] = __builtin_amdgcn_mfma_f32_16x16x32_f16(
                    fr[q], bf, acc[q][nt], 0, 0, 0);
        }
    }

    // ---- y writes (identical layout to round 10) ----
#pragma unroll
    for (int q = 0; q < 4; ++q) {
        const int vox = wv * 16 + q * 4 + ksel;
        const int cbase = (wv + 2) * 80 + (ksel + 2) * 10 + (q + 2);
        f16 xc0 = xs1[0 * 656 + cbase], xc1 = xs1[1 * 656 + cbase];
        f16 xc2 = xs1[2 * 656 + cbase], xc3 = xs1[3 * 656 + cbase];
        const bool ism0 = (am == 0);
        {
            f16x4 yw = {(f16)acc[q][0][0], (f16)acc[q][1][0], (f16)acc[q][2][0],
                        ism0 ? xc0 : (f16)0.f};
            *(f16x4*)&ybuf[am * 1024 + vox * 16 + ((0 + am) & 3) * 4] = yw;
        }
        {
            f16x4 yw = {(f16)acc[q][0][1], (f16)acc[q][1][1], (f16)acc[q][2][1],
                        ism0 ? xc1 : (f16)0.f};
            *(f16x4*)&ybuf[am * 1024 + vox * 16 + ((1 + am) & 3) * 4] = yw;
        }
        {
            f16x4 yw = {(f16)acc[q][0][2], (f16)acc[q][1][2], (f16)acc[q][2][2],
                        ism0 ? xc2 : (f16)0.f};
            *(f16x4*)&ybuf[am * 1024 + vox * 16 + ((2 + am) & 3) * 4] = yw;
        }
        {
            f16x4 yw = {(f16)acc[q][0][3], (f16)acc[q][1][3], (f16)acc[q][2][3],
                        ism0 ? xc3 : (f16)0.f};
            *(f16x4*)&ybuf[am * 1024 + vox * 16 + ((3 + am) & 3) * 4] = yw;
        }
    }

    // ---- stage 2 (same-wave y consumption; no barrier needed) ----
    const int degmap[16] = {0,1,1,1,2,2,2,2,2,3,3,3,3,3,3,3};
    const float bcpv = b_cp[am];
    f32x4 spec[4];
#pragma unroll
    for (int n = 0; n < 4; ++n) spec[n] = (f32x4){0.f, 0.f, 0.f, 0.f};

#if __has_builtin(__builtin_amdgcn_mfma_f32_16x16x16f16)
#pragma unroll
    for (int map = 0; map < 16; ++map) {
        f16x4 ya = *(const f16x4*)&ybuf[map * 1024 + (wv * 16 + am) * 16 + ksel * 4];
        f16x4 wa = *(const f16x4*)&w2g[map * 256 + am * 16 + ksel * 4];
        f32x4 d2 = __builtin_amdgcn_mfma_f32_16x16x16f16(
            ya, wa, (f32x4){0.f, 0.f, 0.f, 0.f}, 0, 0, 0);
        if (map == 0) {
            f32x4 bb = {bcpv, bcpv, bcpv, bcpv};
            d2 = d2 + bb;
        }
        spec[degmap[map]] += d2 * d2;
    }
#else
#pragma unroll
    for (int map = 0; map < 16; ++map) {
        f16x8 yl = *(const f16x8*)&ybuf[map * 1024 + (wv * 16 + am) * 16 + (ksel & 1) * 8];
        f16x8 wl = *(const f16x8*)&w2g[map * 256 + am * 16 + (ksel & 1) * 8];
        f16x8 zz8 = (f16x8){(f16)0.f,(f16)0.f,(f16)0.f,(f16)0.f,
                            (f16)0.f,(f16)0.f,(f16)0.f,(f16)0.f};
        f16x8 ya = (ksel < 2) ? yl : zz8;
        f16x8 wa = (ksel < 2) ? wl : zz8;
        f32x4 d2 = __builtin_amdgcn_mfma_f32_16x16x32_f16(
            ya, wa, (f32x4){0.f, 0.f, 0.f, 0.f}, 0, 0, 0);
        if (map == 0) {
            f32x4 bb = {bcpv, bcpv, bcpv, bcpv};
            d2 = d2 + bb;
        }
        spec[degmap[map]] += d2 * d2;
    }
#endif

    // ---- bias + signed-log in regs ----
    const f32x4 bias4 = *(const f32x4*)&bias[am * 4];
    f16x4 srow[4];
#pragma unroll
    for (int r = 0; r < 4; ++r) {
#pragma unroll
        for (int n = 0; n < 4; ++n) {
            float v = spec[n][r] + bias4[n];
            float lg = __builtin_amdgcn_logf(1.f + fabsf(v)) * 0.69314718055994531f;
            srow[r][n] = (f16)copysignf(lg, v);
        }
    }
    __syncthreads();  // all waves done reading y before s16 overlay writes
#pragma unroll
    for (int r = 0; r < 4; ++r) {
        const int vox = wv * 16 + ksel * 4 + r;
        *(f16x4*)&s16[vox * 72 + am * 4] = srow[r];
    }

    // ---- projection via MFMA: s16[64][64] x w_proj[64][16] ----
    const int fo = am, kg = ksel;
    f16 wb0[8], wb1[8];
#pragma unroll
    for (int j = 0; j < 8; ++j) {
        wb0[j] = (f16)w_proj[(kg * 8 + j) * F_ + fo];
        wb1[j] = (f16)w_proj[(32 + kg * 8 + j) * F_ + fo];
    }
    const float bpj = b_proj[fo];

    f16x8 a0 = *(const f16x8*)&s16[(wv * 16 + am) * 72 + kg * 8];
    f16x8 a1 = *(const f16x8*)&s16[(wv * 16 + am) * 72 + 32 + kg * 8];
    f32x4 oc = {0.f, 0.f, 0.f, 0.f};
    oc = __builtin_amdgcn_mfma_f32_16x16x32_f16(a0, *(f16x8*)wb0, oc, 0, 0, 0);
    oc = __builtin_amdgcn_mfma_f32_16x16x32_f16(a1, *(f16x8*)wb1, oc, 0, 0, 0);

    // D rows = kg*4+r -> vox = wv*16+kg*4+r -> (vd=wv, vw=kg, vh=r)
#pragma unroll
    for (int r = 0; r < 4; ++r) {
        float o = fmaxf(oc[r] + bpj, 0.f);
        out[(((b * NVOX + d0 + wv) * NVOX + (h0 + r)) * NVOX + (w0 + kg)) * F_ + fo] = o;
    }
}

extern "C" void kernel_launch(void* const* d_in, const int* in_sizes, int n_in,
                              void* d_out, int out_size, void* d_ws, size_t ws_size,
                              hipStream_t stream) {
    const float* x = (const float*)d_in[0];       // [2,48,48,48,4]
    const float* w = (const float*)d_in[1];       // [4,16,3,4]
    const float* w_cp = (const float*)d_in[2];    // [4,16]
    const float* b_cp = (const float*)d_in[3];    // [16]
    const float* bias = (const float*)d_in[4];    // [64]
    const float* w_proj = (const float*)d_in[5];  // [64,16]
    const float* b_proj = (const float*)d_in[6];  // [16]
    float* out = (float*)d_out;                   // [2,48,48,48,16]
    f16* ws = (f16*)d_ws;                         // ag 6144 + w2g 4096 f16

    build_filters<<<40, 256, 0, stream>>>(w, w_cp, ws);
    sshconv_main<<<3456, 256, 0, stream>>>(x, ws, ws + 6144, b_cp, bias,
                                           w_proj, b_proj, out);
}